// Round 5
// baseline (343.746 us; speedup 1.0000x reference)
//
#include <hip/hip_runtime.h>
#include <math.h>

#define HID 128
#define NNODES 1023
#define NLEAVES 512

typedef __attribute__((ext_vector_type(8))) short short8;   // 8 bf16
typedef __attribute__((ext_vector_type(4))) short short4v;  // 4 bf16
typedef __attribute__((ext_vector_type(4))) float f32x4;

__device__ __forceinline__ unsigned short f2bf(float f) {   // fp32 -> bf16 RNE
    unsigned int u = __float_as_uint(f);
    u += 0x7FFFu + ((u >> 16) & 1u);
    return (unsigned short)(u >> 16);
}
__device__ __forceinline__ float bf2f(unsigned short s) {
    return __uint_as_float(((unsigned int)s) << 16);
}
__device__ __forceinline__ void pack_hilo(float a, float c, unsigned& h, unsigned& l) {
    const unsigned short ha = f2bf(a), hc = f2bf(c);
    const unsigned short la = f2bf(a - bf2f(ha)), lc = f2bf(c - bf2f(hc));
    h = (unsigned)ha | ((unsigned)hc << 16);
    l = (unsigned)la | ((unsigned)lc << 16);
}

// Vp fragment layout (bf16 elems), 2^17 elems per k (hi+lo):
//  off(k,ihalf,ks,it,hl,lane,e) = k*131072 + ((ihalf*8+ks)*8+it)*1024 + hl*512 + lane*8 + e
//  holding V[k][ihalf*128 + it*16 + (lane&15)][ks*32 + (lane>>4)*8 + e]
__global__ void conv_kernel(const float* __restrict__ V, const float* __restrict__ W,
                            unsigned short* __restrict__ Vp, float* __restrict__ Wt) {
    const int ihalf = blockIdx.x, k = blockIdx.y;
    const int t = threadIdx.x, w = t >> 6, lane = t & 63;
    const int colsel = lane & 15, kg = lane >> 4;
    const size_t srcK = (size_t)k << 16;
    const size_t dstK = (size_t)k << 17;
#pragma unroll
    for (int fi = 0; fi < 16; ++fi) {
        const int frag = w * 16 + fi, ks = frag >> 3, it = frag & 7;
        const int irow = ihalf * 128 + it * 16 + colsel;
        const int j0 = ks * 32 + kg * 8;
        const float4 s0 = *(const float4*)&V[srcK + (size_t)irow * 256 + j0];
        const float4 s1 = *(const float4*)&V[srcK + (size_t)irow * 256 + j0 + 4];
        uint4 ph, pl;
        pack_hilo(s0.x, s0.y, ph.x, pl.x);
        pack_hilo(s0.z, s0.w, ph.y, pl.y);
        pack_hilo(s1.x, s1.y, ph.z, pl.z);
        pack_hilo(s1.z, s1.w, ph.w, pl.w);
        const size_t d = dstK + (size_t)((ihalf * 8 + ks) * 8 + it) * 1024 + lane * 8;
        *(uint4*)&Vp[d] = ph;
        *(uint4*)&Vp[d + 512] = pl;
    }
    if (ihalf == 0) Wt[(size_t)k * 256 + t] = W[(size_t)t * HID + k];  // Wt[k][i]
}

__global__ void leaf_kernel(const float* __restrict__ embed,
                            const int* __restrict__ word_ids,
                            float* __restrict__ H) {
    const int t = blockIdx.x, h = threadIdx.x;
    H[(size_t)t * HID + h] = embed[(size_t)word_ids[t] * HID + h];
}

// Block = 4 waves: wave w -> (kslot=w>>1, ihalf=w&1); covers NR*16 nodes, 2 k's.
// A = V fragments (from permuted global, coalesced), B = X (LDS, swizzled).
// acc[nr][it] = Z'[i,n] = W[i,k] + sum_j X[n,j]V[k,i,j] via 3 bf16 MFMAs (hh, lh, hl).
// q[n] = sum_i X[n,i] * Z'[i,n];  H[n,k] = tanh(q + b[k]).
template<int NR>
__global__ __launch_bounds__(256, 2)
void level_mfma(const unsigned short* __restrict__ Vp, const float* __restrict__ Wt,
                const float* __restrict__ b, const int* __restrict__ left,
                const int* __restrict__ right, float* __restrict__ H,
                int levelStart, int nn) {
    constexpr int ROWS = NR * 16;
    __shared__ __align__(16) unsigned short Xh[ROWS * 256];
    __shared__ __align__(16) unsigned short Xl[ROWS * 256];
    __shared__ float qred[2 * 64 * 2];

    const int t = threadIdx.x;
    // flat -> (tile gxv, kpair gyv) with kpair>>3 pinned to XCD (flat%8 round-robin)
    const int fl = blockIdx.x + gridDim.x * blockIdx.y;
    const int gX = gridDim.x;
    const int xcd = fl & 7, r2 = fl >> 3;
    const int gxv = r2 % gX;
    const int gyv = xcd * 8 + r2 / gX;      // 0..63
    const int k0 = gyv * 2;
    const int w = t >> 6, lane = t & 63;
    const int kslot = w >> 1, ihalf = w & 1;
    const int k = k0 + kslot;
    const int colsel = lane & 15, kg = lane >> 4;
    const size_t kbase = (size_t)k << 17;
    const int n0 = gxv * ROWS;

    // ---- stage X = concat(H[l],H[r]) hi/lo bf16, swizzle elems ^((row&7)<<3) ----
    for (int idx = t; idx < ROWS * 32; idx += 256) {
        const int row = idx >> 5, i0 = (idx & 31) * 8, n = n0 + row;
        uint4 ph = make_uint4(0u, 0u, 0u, 0u), pl = ph;
        if (n < nn) {
            const int node = levelStart + n;
            const int child = (i0 < HID) ? left[node] : right[node];
            const float4* hp = (const float4*)&H[(size_t)child * HID + (i0 & 127)];
            const float4 x0 = hp[0], x1 = hp[1];
            pack_hilo(x0.x, x0.y, ph.x, pl.x);
            pack_hilo(x0.z, x0.w, ph.y, pl.y);
            pack_hilo(x1.x, x1.y, ph.z, pl.z);
            pack_hilo(x1.z, x1.w, ph.w, pl.w);
        }
        const int ad = (row * 256 + i0) ^ ((row & 7) << 3);
        *(uint4*)&Xh[ad] = ph;
        *(uint4*)&Xl[ad] = pl;
    }
    __syncthreads();

    // ---- acc init = W[i,k] (same for every node column) ----
    f32x4 acc[NR][8];
#pragma unroll
    for (int it = 0; it < 8; ++it) {
        const f32x4 wv = *(const f32x4*)&Wt[(size_t)k * 256 + ihalf * 128 + it * 16 + kg * 4];
#pragma unroll
        for (int nr = 0; nr < NR; ++nr) acc[nr][it] = wv;
    }

    // ---- K-loop over j ----
#pragma unroll
    for (int ks = 0; ks < 8; ++ks) {
        short8 xh[NR], xl[NR];
#pragma unroll
        for (int nr = 0; nr < NR; ++nr) {
            const int row = nr * 16 + colsel;
            const int ad = (row * 256 + ks * 32 + kg * 8) ^ ((row & 7) << 3);
            xh[nr] = *(const short8*)&Xh[ad];
            xl[nr] = *(const short8*)&Xl[ad];
        }
        const size_t fb = kbase + (size_t)((ihalf * 8 + ks) * 8) * 1024 + lane * 8;
#pragma unroll
        for (int it = 0; it < 8; ++it) {
            const short8 vh = *(const short8*)&Vp[fb + it * 1024];
            const short8 vl = *(const short8*)&Vp[fb + it * 1024 + 512];
#pragma unroll
            for (int nr = 0; nr < NR; ++nr) {
                acc[nr][it] = __builtin_amdgcn_mfma_f32_16x16x32_bf16(vh, xh[nr], acc[nr][it], 0, 0, 0);
                acc[nr][it] = __builtin_amdgcn_mfma_f32_16x16x32_bf16(vl, xh[nr], acc[nr][it], 0, 0, 0);
                acc[nr][it] = __builtin_amdgcn_mfma_f32_16x16x32_bf16(vh, xl[nr], acc[nr][it], 0, 0, 0);
            }
        }
    }

    // ---- epilogue: q[n] = sum_i X[n,i]*Z'[i,n]; D: row(i)=it*16+kg*4+r, col(n)=nr*16+colsel
    float qp[NR];
#pragma unroll
    for (int nr = 0; nr < NR; ++nr) qp[nr] = 0.f;
#pragma unroll
    for (int it = 0; it < 8; ++it) {
        const int i0 = ihalf * 128 + it * 16 + kg * 4;
#pragma unroll
        for (int nr = 0; nr < NR; ++nr) {
            const int row = nr * 16 + colsel;
            const int ad = (row * 256 + i0) ^ ((row & 7) << 3);
            const short4v h4 = *(const short4v*)&Xh[ad];
            const short4v l4 = *(const short4v*)&Xl[ad];
#pragma unroll
            for (int r = 0; r < 4; ++r) {
                const float x = bf2f((unsigned short)h4[r]) + bf2f((unsigned short)l4[r]);
                qp[nr] = fmaf(x, acc[nr][it][r], qp[nr]);
            }
        }
    }
#pragma unroll
    for (int nr = 0; nr < NR; ++nr) {
        qp[nr] += __shfl_xor(qp[nr], 16, 64);
        qp[nr] += __shfl_xor(qp[nr], 32, 64);
    }
    if (kg == 0) {
#pragma unroll
        for (int nr = 0; nr < NR; ++nr)
            qred[(kslot * 64 + nr * 16 + colsel) * 2 + ihalf] = qp[nr];
    }
    __syncthreads();
    if (t < 128) {
        const int ksl = t >> 6, n = t & 63;
        if (n < ROWS && n0 + n < nn) {
            const float s = b[k0 + ksl] + qred[(ksl * 64 + n) * 2 + 0]
                                        + qred[(ksl * 64 + n) * 2 + 1];
            H[(size_t)(levelStart + n0 + n) * HID + (k0 + ksl)] = tanhf(s);
        }
    }
}

__global__ void out_kernel(const float* __restrict__ H,
                           const float* __restrict__ Wout,
                           const float* __restrict__ bout,
                           float* __restrict__ out) {
    const int t = blockIdx.x, l = threadIdx.x;
    const float h0 = H[(size_t)t * HID + l];
    const float h1 = H[(size_t)t * HID + 64 + l];
    float p[5];
#pragma unroll
    for (int o = 0; o < 5; ++o) {
        p[o] = h0 * Wout[o * HID + l] + h1 * Wout[o * HID + 64 + l];
#pragma unroll
        for (int m = 1; m < 64; m <<= 1) p[o] += __shfl_xor(p[o], m, 64);
    }
    if (l == 0) {
        float lg[5], mx = -1e30f;
#pragma unroll
        for (int o = 0; o < 5; ++o) { lg[o] = p[o] + bout[o]; mx = fmaxf(mx, lg[o]); }
        float s = 0.f;
#pragma unroll
        for (int o = 0; o < 5; ++o) s += expf(lg[o] - mx);
        const float lse = mx + logf(s);
#pragma unroll
        for (int o = 0; o < 5; ++o) out[(size_t)t * 5 + o] = lg[o] - lse;
    }
}

extern "C" void kernel_launch(void* const* d_in, const int* in_sizes, int n_in,
                              void* d_out, int out_size, void* d_ws, size_t ws_size,
                              hipStream_t stream) {
    const float* embed   = (const float*)d_in[0];
    const float* V       = (const float*)d_in[1];
    const float* W       = (const float*)d_in[2];
    const float* b       = (const float*)d_in[3];
    const float* Woutw   = (const float*)d_in[4];
    const float* Woutb   = (const float*)d_in[5];
    const int*   wordids = (const int*)d_in[6];
    const int*   left    = (const int*)d_in[7];
    const int*   right   = (const int*)d_in[8];
    // d_in[9] (is_leaf) unused: balanced tree => leaves are exactly t<512.

    unsigned short* Vp = (unsigned short*)d_ws;                     // 128*131072*2B = 33.55 MB
    float* Wt  = (float*)((char*)d_ws + (size_t)128 * 131072 * 2);  // 128*256*4B
    float* H   = Wt + (size_t)128 * 256;                            // 1023*128 fp32
    float* out = (float*)d_out;

    conv_kernel<<<dim3(2, 128), 256, 0, stream>>>(V, W, Vp, Wt);
    leaf_kernel<<<NLEAVES, HID, 0, stream>>>(embed, wordids, H);

    // levels: (start,nn): (512,256)(768,128)(896,64)(960,32)(992,16)(1008,8)(1016,4)(1020,2)(1022,1)
    level_mfma<4><<<dim3(4, 64), 256, 0, stream>>>(Vp, Wt, b, left, right, H, 512, 256);
    level_mfma<4><<<dim3(2, 64), 256, 0, stream>>>(Vp, Wt, b, left, right, H, 768, 128);
    level_mfma<4><<<dim3(1, 64), 256, 0, stream>>>(Vp, Wt, b, left, right, H, 896,  64);
    level_mfma<2><<<dim3(1, 64), 256, 0, stream>>>(Vp, Wt, b, left, right, H, 960,  32);
    level_mfma<1><<<dim3(1, 64), 256, 0, stream>>>(Vp, Wt, b, left, right, H, 992,  16);
    level_mfma<1><<<dim3(1, 64), 256, 0, stream>>>(Vp, Wt, b, left, right, H, 1008,  8);
    level_mfma<1><<<dim3(1, 64), 256, 0, stream>>>(Vp, Wt, b, left, right, H, 1016,  4);
    level_mfma<1><<<dim3(1, 64), 256, 0, stream>>>(Vp, Wt, b, left, right, H, 1020,  2);
    level_mfma<1><<<dim3(1, 64), 256, 0, stream>>>(Vp, Wt, b, left, right, H, 1022,  1);

    out_kernel<<<NNODES, 64, 0, stream>>>(H, Woutw, Woutb, out);
}